// Round 12
// baseline (291.942 us; speedup 1.0000x reference)
//
#include <hip/hip_runtime.h>
#include <stdint.h>

typedef __bf16 bf16;
typedef __bf16 bf16x2 __attribute__((ext_vector_type(2)));
typedef __bf16 bf16x4 __attribute__((ext_vector_type(4)));
typedef __bf16 bf16x8 __attribute__((ext_vector_type(8)));
typedef float  fx2    __attribute__((ext_vector_type(2)));
typedef float  fx4    __attribute__((ext_vector_type(4)));

#define MFMA16(a, b, c) __builtin_amdgcn_mfma_f32_16x16x32_bf16((a), (b), (c), 0, 0, 0)

// B=4, N=2048, E=768, H=8, D=96; M = B*N = 8192. User tensors fp32, out fp32.

// ---------------------------------------------------------------------------
// Barrier WITHOUT the vmem drain (lgkmcnt(0) only).
// ---------------------------------------------------------------------------
__device__ __forceinline__ void barrier_nodrain() {
  __asm__ __volatile__("" ::: "memory");
  __builtin_amdgcn_s_waitcnt(0xC07F);
  __builtin_amdgcn_s_barrier();
  __asm__ __volatile__("" ::: "memory");
}

// Counted vmem waits: vmcnt[3:0] | exp=7 nowait | lgkm[11:8]=0xF nowait.
__device__ __forceinline__ void wait_vm6() {
  __asm__ __volatile__("" ::: "memory");
  __builtin_amdgcn_s_waitcnt(0x0F76);
  __asm__ __volatile__("" ::: "memory");
}
__device__ __forceinline__ void wait_vm8() {
  __asm__ __volatile__("" ::: "memory");
  __builtin_amdgcn_s_waitcnt(0x0F78);
  __asm__ __volatile__("" ::: "memory");
}
__device__ __forceinline__ void wait_lgkm0() {
  __asm__ __volatile__("" ::: "memory");
  __builtin_amdgcn_s_waitcnt(0xC07F);
  __asm__ __volatile__("" ::: "memory");
}

// DMA 16 B/lane global -> LDS (dest = wave-uniform base + lane*16, m104).
__device__ __forceinline__ void gload_lds16(const void* g, void* l) {
  __builtin_amdgcn_global_load_lds(
      (const __attribute__((address_space(1))) void*)g,
      (__attribute__((address_space(3))) void*)l, 16, 0, 0);
}

// ---------------------------------------------------------------------------
// x (fp32) -> bf16, 4 elems/thread (fallback path).
// ---------------------------------------------------------------------------
__global__ __launch_bounds__(256)
void cvt_x_kernel(const float* __restrict__ x, bf16* __restrict__ xb) {
  const int i = (blockIdx.x * 256 + threadIdx.x) * 4;
  float4 v = *(const float4*)&x[i];
  bf16x4 o;
  o[0] = (bf16)v.x; o[1] = (bf16)v.y; o[2] = (bf16)v.z; o[3] = (bf16)v.w;
  *(bf16x4*)&xb[i] = o;
}

// ---------------------------------------------------------------------------
// R22: merged converter (fast path): blocks 0..6143 convert x (8192x768),
// blocks 6144..8447 convert the 4 weight matrices into contiguous Wb.
// One launch instead of two.
// ---------------------------------------------------------------------------
__global__ __launch_bounds__(256)
void cvt_all_kernel(const float* __restrict__ x,
                    const float* __restrict__ Wq, const float* __restrict__ Wk,
                    const float* __restrict__ Wv, const float* __restrict__ Wo,
                    bf16* __restrict__ xb, bf16* __restrict__ Wb) {
  const int bid = blockIdx.x;
  if (bid < 6144) {
    const int i = (bid * 256 + threadIdx.x) * 4;
    float4 v = *(const float4*)&x[i];
    bf16x4 o;
    o[0] = (bf16)v.x; o[1] = (bf16)v.y; o[2] = (bf16)v.z; o[3] = (bf16)v.w;
    *(bf16x4*)&xb[i] = o;
  } else {
    const int b2 = bid - 6144;         // 0..2303, 576 blocks per matrix
    const int m  = b2 / 576;
    const float* src = (m == 0) ? Wq : (m == 1) ? Wk : (m == 2) ? Wv : Wo;
    const int i = ((b2 - m * 576) * 256 + threadIdx.x) * 4;
    float4 v = *(const float4*)&src[i];
    bf16x4 o;
    o[0] = (bf16)v.x; o[1] = (bf16)v.y; o[2] = (bf16)v.z; o[3] = (bf16)v.w;
    *(bf16x4*)&Wb[(size_t)m * 589824 + i] = o;
  }
}

// ---------------------------------------------------------------------------
// Shared epilogue for QKV: write Q row-major / K,V in attn staging tiles
// (R15-R19 proven 6144-B tile layout):
//   K: [b][h][kt][u=d/8][k32][d%8]   V: [b][h][kt][ku=k/8][d96][k%8]
// ---------------------------------------------------------------------------
__device__ __forceinline__ void qkv_epilogue(
    int sel, int cb0, int rb0, int wc, int wr, int l15, int q4,
    const float* bia, fx4 (&acc)[4][4],
    bf16* Qo, bf16* Ka, bf16* Va) {
  const int cb = cb0 + wc * 64;
  const int rb = rb0 + wr * 64;
#pragma unroll
  for (int j = 0; j < 4; j++) {
    const int o  = cb + j * 16 + l15;
    const float bj = bia[o];
    const int hh = o / 96;
    const int dd = o - hh * 96;
#pragma unroll
    for (int i = 0; i < 4; i++) {
      const int r0 = rb + i * 16 + q4 * 4;
      if (sel == 2) {
        const int bb = r0 >> 11;
        const int n2 = r0 & 2047;
        const size_t flat =
            ((size_t)((bb * 8 + hh) * 64 + (n2 >> 5))) * 3072 +
            ((n2 >> 3) & 3) * 768 + dd * 8 + (n2 & 7);
        bf16x4 pk;
#pragma unroll
        for (int r = 0; r < 4; r++) pk[r] = (bf16)(acc[i][j][r] + bj);
        *(bf16x4*)&Va[flat] = pk;
      } else if (sel == 1) {
        const int u  = dd >> 3;
        const int de = dd & 7;
#pragma unroll
        for (int r = 0; r < 4; r++) {
          const int n  = r0 + r;
          const int bb = n >> 11;
          const int n2 = n & 2047;
          const size_t flat =
              ((size_t)((bb * 8 + hh) * 64 + (n2 >> 5))) * 3072 +
              u * 256 + (n2 & 31) * 8 + de;
          Ka[flat] = (bf16)(acc[i][j][r] + bj);
        }
      } else {
#pragma unroll
        for (int r = 0; r < 4; r++)
          Qo[(size_t)(r0 + r) * 768 + o] = (bf16)(acc[i][j][r] + bj);
      }
    }
  }
}

// ---------------------------------------------------------------------------
// R22 FAST PATH: fused QKV GEMM, A and B DMA-staged with a 3-DEEP pipeline.
// R21 post-mortem: dbuf's prefetch distance = 1 k-step (~250-350 cyc of
// work) < load latency (~200-900 cyc) -> every wait_vm4 exposed the gap,
// 24x/block. Triple buffer (48 KB, 3 blocks/CU) issues stage(k+2) each
// iter: distance ~2 steps covers L2 latency. wait vmcnt(8): tiles k+1,k+2
// (8 loads) stay in flight, tile k's 4 drained. Buffer safety: iter k reads
// buf k%3, stages into (k+2)%3 (disjoint); end-of-iter lgkm barrier retires
// all ds_reads of a buffer before any wave re-stages it; clamped tail
// redoes re-write identical data into retired buffers.
// ---------------------------------------------------------------------------
__global__ __launch_bounds__(256)
void gemm_qkv_bf(const bf16* __restrict__ A, const bf16* __restrict__ Wb,
                 const float* __restrict__ bq, const float* __restrict__ bk,
                 const float* __restrict__ bv,
                 bf16* __restrict__ Qo, bf16* __restrict__ Ka,
                 bf16* __restrict__ Va) {
  constexpr int K = 768;
  __shared__ __align__(16) bf16 As[3][128 * 32];
  __shared__ __align__(16) bf16 Bs[3][128 * 32];

  const int tid  = threadIdx.x;
  const int wave = tid >> 6;
  const int lane = tid & 63;
  const int l15  = lane & 15;
  const int q4   = lane >> 4;
  const int wr   = wave >> 1;
  const int wc   = wave & 1;
  const int sel  = blockIdx.x / 6;
  const int cb0  = (blockIdx.x % 6) * 128;
  const int rb0  = blockIdx.y * 128;

  const bf16*  W   = Wb + (size_t)sel * 589824;
  const float* bia = (sel == 0) ? bq : (sel == 1) ? bk : bv;

  const int ar0 = tid >> 2,  akc0 = (tid & 3) << 3;
  const int ar1 = ar0 + 64;

  fx4 acc[4][4];
#pragma unroll
  for (int i = 0; i < 4; i++)
#pragma unroll
    for (int j = 0; j < 4; j++) acc[i][j] = (fx4){0.f, 0.f, 0.f, 0.f};

  auto stage = [&](int k0, int buf) {
    gload_lds16(&A[(size_t)(rb0 + ar0) * K + k0 + akc0], &As[buf][wave * 512]);
    gload_lds16(&A[(size_t)(rb0 + ar1) * K + k0 + akc0],
                &As[buf][(wave + 4) * 512]);
    gload_lds16(&W[(size_t)(cb0 + ar0) * K + k0 + akc0], &Bs[buf][wave * 512]);
    gload_lds16(&W[(size_t)(cb0 + ar1) * K + k0 + akc0],
                &Bs[buf][(wave + 4) * 512]);
  };

  stage(0, 0);
  stage(32, 1);
  for (int st = 0; st < 24; st++) {
    const int kf = (st + 2 < 24) ? (st + 2) * 32 : 736;  // clamp: benign redo
    stage(kf, (st + 2) % 3);
    wait_vm8();          // tile st's 4 loads landed; 8 newer stay in flight
    barrier_nodrain();

    const int cur = st % 3;
    bf16x8 a[4], b[4];
#pragma unroll
    for (int i = 0; i < 4; i++)
      a[i] = *(const bf16x8*)&As[cur][(wr * 64 + i * 16 + l15) * 32 + q4 * 8];
#pragma unroll
    for (int j = 0; j < 4; j++)
      b[j] = *(const bf16x8*)&Bs[cur][(wc * 64 + j * 16 + l15) * 32 + q4 * 8];
#pragma unroll
    for (int i = 0; i < 4; i++)
#pragma unroll
      for (int j = 0; j < 4; j++)
        acc[i][j] = MFMA16(a[i], b[j], acc[i][j]);

    barrier_nodrain();   // own ds_reads retired before this buf is re-staged
  }
  __builtin_amdgcn_s_waitcnt(0x0070);  // drain redundant tail DMA

  qkv_epilogue(sel, cb0, rb0, wc, wr, l15, q4, bia, acc, Qo, Ka, Va);
}

// ---------------------------------------------------------------------------
// R22 FAST PATH: output projection, same 3-deep pipeline.
// ---------------------------------------------------------------------------
__global__ __launch_bounds__(256)
void gemm_o_bf(const bf16* __restrict__ A, const bf16* __restrict__ W,
               const float* __restrict__ bias, float* __restrict__ C) {
  constexpr int K = 768;
  __shared__ __align__(16) bf16 As[3][128 * 32];
  __shared__ __align__(16) bf16 Bs[3][128 * 32];

  const int tid  = threadIdx.x;
  const int wave = tid >> 6;
  const int lane = tid & 63;
  const int l15  = lane & 15;
  const int q4   = lane >> 4;
  const int wr   = wave >> 1;
  const int wc   = wave & 1;
  const int rb0  = blockIdx.y * 128;
  const int cb0  = blockIdx.x * 128;

  const int ar0 = tid >> 2,  akc0 = (tid & 3) << 3;
  const int ar1 = ar0 + 64;

  fx4 acc[4][4];
#pragma unroll
  for (int i = 0; i < 4; i++)
#pragma unroll
    for (int j = 0; j < 4; j++) acc[i][j] = (fx4){0.f, 0.f, 0.f, 0.f};

  auto stage = [&](int k0, int buf) {
    gload_lds16(&A[(size_t)(rb0 + ar0) * K + k0 + akc0], &As[buf][wave * 512]);
    gload_lds16(&A[(size_t)(rb0 + ar1) * K + k0 + akc0],
                &As[buf][(wave + 4) * 512]);
    gload_lds16(&W[(size_t)(cb0 + ar0) * K + k0 + akc0], &Bs[buf][wave * 512]);
    gload_lds16(&W[(size_t)(cb0 + ar1) * K + k0 + akc0],
                &Bs[buf][(wave + 4) * 512]);
  };

  stage(0, 0);
  stage(32, 1);
  for (int st = 0; st < 24; st++) {
    const int kf = (st + 2 < 24) ? (st + 2) * 32 : 736;
    stage(kf, (st + 2) % 3);
    wait_vm8();
    barrier_nodrain();

    const int cur = st % 3;
    bf16x8 a[4], b[4];
#pragma unroll
    for (int i = 0; i < 4; i++)
      a[i] = *(const bf16x8*)&As[cur][(wr * 64 + i * 16 + l15) * 32 + q4 * 8];
#pragma unroll
    for (int j = 0; j < 4; j++)
      b[j] = *(const bf16x8*)&Bs[cur][(wc * 64 + j * 16 + l15) * 32 + q4 * 8];
#pragma unroll
    for (int i = 0; i < 4; i++)
#pragma unroll
      for (int j = 0; j < 4; j++)
        acc[i][j] = MFMA16(a[i], b[j], acc[i][j]);

    barrier_nodrain();
  }
  __builtin_amdgcn_s_waitcnt(0x0070);

  const int cb = cb0 + wc * 64;
  const int rb = rb0 + wr * 64;
#pragma unroll
  for (int j = 0; j < 4; j++) {
    const int o  = cb + j * 16 + l15;
    const float bj = bias[o];
#pragma unroll
    for (int i = 0; i < 4; i++) {
      const int r0 = rb + i * 16 + q4 * 4;
#pragma unroll
      for (int r = 0; r < 4; r++)
        C[(size_t)(r0 + r) * 768 + o] = acc[i][j][r] + bj;
    }
  }
}

// ---------------------------------------------------------------------------
// FALLBACK (R17, proven): A DMA dbuf, B coalesced fp32-cvt staging.
// ---------------------------------------------------------------------------
__global__ __launch_bounds__(256)
void gemm_qkv(const bf16* __restrict__ A,
              const float* __restrict__ Wq, const float* __restrict__ Wk,
              const float* __restrict__ Wv,
              const float* __restrict__ bq, const float* __restrict__ bk,
              const float* __restrict__ bv,
              bf16* __restrict__ Qo, bf16* __restrict__ Ka,
              bf16* __restrict__ Va) {
  constexpr int K = 768;
  __shared__ __align__(16) bf16 As[2][128 * 32];
  __shared__ __align__(16) bf16 Bs[128 * 32];

  const int tid  = threadIdx.x;
  const int wave = tid >> 6;
  const int lane = tid & 63;
  const int l15  = lane & 15;
  const int q4   = lane >> 4;
  const int wr   = wave >> 1;
  const int wc   = wave & 1;
  const int sel  = blockIdx.x / 6;
  const int cb0  = (blockIdx.x % 6) * 128;
  const int rb0  = blockIdx.y * 128;

  const float* W   = (sel == 0) ? Wq : (sel == 1) ? Wk : Wv;
  const float* bia = (sel == 0) ? bq : (sel == 1) ? bk : bv;

  const int ar0 = tid >> 2,  akc0 = (tid & 3) << 3;
  const int ar1 = ar0 + 64;

  fx4 acc[4][4];
#pragma unroll
  for (int i = 0; i < 4; i++)
#pragma unroll
    for (int j = 0; j < 4; j++) acc[i][j] = (fx4){0.f, 0.f, 0.f, 0.f};

  gload_lds16(&A[(size_t)(rb0 + ar0) * K + akc0], &As[0][wave * 512]);
  gload_lds16(&A[(size_t)(rb0 + ar1) * K + akc0], &As[0][(wave + 4) * 512]);

  int cur = 0;
  for (int k0 = 0; k0 < K; k0 += 32, cur ^= 1) {
    const float* wp0 = W + (size_t)(cb0 + ar0) * K + k0 + akc0;
    const float* wp1 = W + (size_t)(cb0 + ar1) * K + k0 + akc0;
    const float4 b0a = *(const float4*)wp0;
    const float4 b0b = *(const float4*)(wp0 + 4);
    const float4 b1a = *(const float4*)wp1;
    const float4 b1b = *(const float4*)(wp1 + 4);
    __asm__ __volatile__("" ::: "memory");

    const int kn = (k0 + 32 < K) ? k0 + 32 : k0;
    gload_lds16(&A[(size_t)(rb0 + ar0) * K + kn + akc0],
                &As[cur ^ 1][wave * 512]);
    gload_lds16(&A[(size_t)(rb0 + ar1) * K + kn + akc0],
                &As[cur ^ 1][(wave + 4) * 512]);
    __asm__ __volatile__("" ::: "memory");

    bf16x8 pb0, pb1;
    pb0[0] = (bf16)b0a.x; pb0[1] = (bf16)b0a.y;
    pb0[2] = (bf16)b0a.z; pb0[3] = (bf16)b0a.w;
    pb0[4] = (bf16)b0b.x; pb0[5] = (bf16)b0b.y;
    pb0[6] = (bf16)b0b.z; pb0[7] = (bf16)b0b.w;
    pb1[0] = (bf16)b1a.x; pb1[1] = (bf16)b1a.y;
    pb1[2] = (bf16)b1a.z; pb1[3] = (bf16)b1a.w;
    pb1[4] = (bf16)b1b.x; pb1[5] = (bf16)b1b.y;
    pb1[6] = (bf16)b1b.z; pb1[7] = (bf16)b1b.w;
    *(bf16x8*)&Bs[ar0 * 32 + akc0] = pb0;
    *(bf16x8*)&Bs[ar1 * 32 + akc0] = pb1;

    barrier_nodrain();

    bf16x8 a[4], b[4];
#pragma unroll
    for (int i = 0; i < 4; i++)
      a[i] = *(const bf16x8*)&As[cur][(wr * 64 + i * 16 + l15) * 32 + q4 * 8];
#pragma unroll
    for (int j = 0; j < 4; j++)
      b[j] = *(const bf16x8*)&Bs[(wc * 64 + j * 16 + l15) * 32 + q4 * 8];
#pragma unroll
    for (int i = 0; i < 4; i++)
#pragma unroll
      for (int j = 0; j < 4; j++)
        acc[i][j] = MFMA16(a[i], b[j], acc[i][j]);

    barrier_nodrain();
  }

  qkv_epilogue(sel, cb0, rb0, wc, wr, l15, q4, bia, acc, Qo, Ka, Va);
}

__global__ __launch_bounds__(256)
void gemm_o(const bf16* __restrict__ A, const float* __restrict__ W,
            const float* __restrict__ bias, float* __restrict__ C) {
  constexpr int K = 768;
  __shared__ __align__(16) bf16 As[2][128 * 32];
  __shared__ __align__(16) bf16 Bs[128 * 32];

  const int tid  = threadIdx.x;
  const int wave = tid >> 6;
  const int lane = tid & 63;
  const int l15  = lane & 15;
  const int q4   = lane >> 4;
  const int wr   = wave >> 1;
  const int wc   = wave & 1;
  const int rb0  = blockIdx.y * 128;
  const int cb0  = blockIdx.x * 128;

  const int ar0 = tid >> 2,  akc0 = (tid & 3) << 3;
  const int ar1 = ar0 + 64;

  fx4 acc[4][4];
#pragma unroll
  for (int i = 0; i < 4; i++)
#pragma unroll
    for (int j = 0; j < 4; j++) acc[i][j] = (fx4){0.f, 0.f, 0.f, 0.f};

  gload_lds16(&A[(size_t)(rb0 + ar0) * K + akc0], &As[0][wave * 512]);
  gload_lds16(&A[(size_t)(rb0 + ar1) * K + akc0], &As[0][(wave + 4) * 512]);

  int cur = 0;
  for (int k0 = 0; k0 < K; k0 += 32, cur ^= 1) {
    const float* wp0 = W + (size_t)(cb0 + ar0) * K + k0 + akc0;
    const float* wp1 = W + (size_t)(cb0 + ar1) * K + k0 + akc0;
    const float4 b0a = *(const float4*)wp0;
    const float4 b0b = *(const float4*)(wp0 + 4);
    const float4 b1a = *(const float4*)wp1;
    const float4 b1b = *(const float4*)(wp1 + 4);
    __asm__ __volatile__("" ::: "memory");

    const int kn = (k0 + 32 < K) ? k0 + 32 : k0;
    gload_lds16(&A[(size_t)(rb0 + ar0) * K + kn + akc0],
                &As[cur ^ 1][wave * 512]);
    gload_lds16(&A[(size_t)(rb0 + ar1) * K + kn + akc0],
                &As[cur ^ 1][(wave + 4) * 512]);
    __asm__ __volatile__("" ::: "memory");

    bf16x8 pb0, pb1;
    pb0[0] = (bf16)b0a.x; pb0[1] = (bf16)b0a.y;
    pb0[2] = (bf16)b0a.z; pb0[3] = (bf16)b0a.w;
    pb0[4] = (bf16)b0b.x; pb0[5] = (bf16)b0b.y;
    pb0[6] = (bf16)b0b.z; pb0[7] = (bf16)b0b.w;
    pb1[0] = (bf16)b1a.x; pb1[1] = (bf16)b1a.y;
    pb1[2] = (bf16)b1a.z; pb1[3] = (bf16)b1a.w;
    pb1[4] = (bf16)b1b.x; pb1[5] = (bf16)b1b.y;
    pb1[6] = (bf16)b1b.z; pb1[7] = (bf16)b1b.w;
    *(bf16x8*)&Bs[ar0 * 32 + akc0] = pb0;
    *(bf16x8*)&Bs[ar1 * 32 + akc0] = pb1;

    barrier_nodrain();

    bf16x8 a[4], b[4];
#pragma unroll
    for (int i = 0; i < 4; i++)
      a[i] = *(const bf16x8*)&As[cur][(wr * 64 + i * 16 + l15) * 32 + q4 * 8];
#pragma unroll
    for (int j = 0; j < 4; j++)
      b[j] = *(const bf16x8*)&Bs[(wc * 64 + j * 16 + l15) * 32 + q4 * 8];
#pragma unroll
    for (int i = 0; i < 4; i++)
#pragma unroll
      for (int j = 0; j < 4; j++)
        acc[i][j] = MFMA16(a[i], b[j], acc[i][j]);

    barrier_nodrain();
  }

  const int cb = cb0 + wc * 64;
  const int rb = rb0 + wr * 64;
#pragma unroll
  for (int j = 0; j < 4; j++) {
    const int o  = cb + j * 16 + l15;
    const float bj = bias[o];
#pragma unroll
    for (int i = 0; i < 4; i++) {
      const int r0 = rb + i * 16 + q4 * 4;
#pragma unroll
      for (int r = 0; r < 4; r++)
        C[(size_t)(r0 + r) * 768 + o] = acc[i][j][r] + bj;
    }
  }
}

// ---------------------------------------------------------------------------
// Attention (R19, proven 139.8 µs). Softmax over HEADS (dim=1), / sqrt(768).
// Swapped QK^T (E^T), vectorized b128 scatter, k-pair softmax, bf16 Pbuf.
// DMA K/V staging, counted vm6, nodrain barriers.
// LDS: 48 + 48 + 32.5 + 20 = 148.5 KB (1 block/CU).
// ---------------------------------------------------------------------------
__global__ __launch_bounds__(512, 1)
void attn_kernel(const bf16* Q, const bf16* __restrict__ Ka,
                 const bf16* __restrict__ Va, bf16* AO) {
  __shared__ __align__(16) bf16  Kbuf[8 * 3072];   // [h][u12][k32][8] 48 KB
  __shared__ __align__(16) bf16  Vbuf[8 * 3072];   // [h][ku4][d96][8] 48 KB
  __shared__ __align__(16) float Ebuf[32 * 260];   // [q][h*32+k]    32.5 KB
  __shared__ __align__(16) bf16  Pbuf[8 * 32 * 40]; // [h][q][k pad40] 20 KB

  const int tid  = threadIdx.x;
  const int h    = tid >> 6;
  const int lane = tid & 63;
  const int l15  = lane & 15;
  const int q4   = lane >> 4;
  const int b    = blockIdx.x >> 6;
  const int qt   = blockIdx.x & 63;
  const int qrow0 = b * 2048 + qt * 32;

  bf16x8 aq[2][3];
#pragma unroll
  for (int i = 0; i < 2; i++)
#pragma unroll
    for (int c = 0; c < 3; c++)
      aq[i][c] = *(const bf16x8*)
          &Q[(size_t)(qrow0 + i * 16 + l15) * 768 + h * 96 + c * 32 + q4 * 8];

  fx4 o[2][6];
#pragma unroll
  for (int i = 0; i < 2; i++)
#pragma unroll
    for (int j = 0; j < 6; j++) o[i][j] = (fx4){0.f, 0.f, 0.f, 0.f};

  const bf16* Kt0 = Ka + (size_t)(b * 8 + h) * 64 * 3072;
  const bf16* Vt0 = Va + (size_t)(b * 8 + h) * 64 * 3072;
  bf16* Kl = &Kbuf[h * 3072];
  bf16* Vl = &Vbuf[h * 3072];

  auto stageK = [&](int kt) {
    const bf16* src = Kt0 + (size_t)kt * 3072 + lane * 8;
#pragma unroll
    for (int t = 0; t < 6; t++)
      gload_lds16(src + t * 512, Kl + t * 512);
  };
  auto stageV = [&](int kt) {
    const bf16* src = Vt0 + (size_t)kt * 3072 + lane * 8;
#pragma unroll
    for (int t = 0; t < 6; t++)
      gload_lds16(src + t * 512, Vl + t * 512);
  };

  stageK(0);
  stageV(0);

  for (int kt = 0; kt < 64; kt++) {
    const int kn = (kt + 1 < 64) ? kt + 1 : 63;

    wait_vm6();

    bf16x8 bk[2][3];
#pragma unroll
    for (int j = 0; j < 2; j++)
#pragma unroll
      for (int c = 0; c < 3; c++)
        bk[j][c] =
            *(const bf16x8*)&Kl[(c * 4 + q4) * 256 + (j * 16 + l15) * 8];

    wait_lgkm0();
    stageK(kn);

    // E^T = K Q^T (swapped): lane owns q = i*16+l15, k = j*16+q4*4+r.
    fx4 e2[2][2];
    e2[0][0] = e2[0][1] = e2[1][0] = e2[1][1] = (fx4){0.f, 0.f, 0.f, 0.f};
    __builtin_amdgcn_s_setprio(1);
#pragma unroll
    for (int c = 0; c < 3; c++)
#pragma unroll
      for (int j = 0; j < 2; j++) {
        e2[j][0] = MFMA16(bk[j][c], aq[0][c], e2[j][0]);
        e2[j][1] = MFMA16(bk[j][c], aq[1][c], e2[j][1]);
      }
    __builtin_amdgcn_s_setprio(0);

#pragma unroll
    for (int i = 0; i < 2; i++)
#pragma unroll
      for (int j = 0; j < 2; j++)
        *(fx4*)&Ebuf[(i * 16 + l15) * 260 + h * 32 + j * 16 + q4 * 4] =
            e2[j][i];
    barrier_nodrain();

    // Softmax over heads, (q, 2 adjacent k) per thread.
    {
      const int q  = tid >> 4;
      const int k2 = (tid & 15) << 1;
      const float* row = &Ebuf[q * 260 + k2];
      fx2 v[8];
#pragma unroll
      for (int hh = 0; hh < 8; hh++) v[hh] = *(const fx2*)&row[hh * 32];
      fx2 m = v[0];
#pragma unroll
      for (int hh = 1; hh < 8; hh++) {
        m[0] = fmaxf(m[0], v[hh][0]);
        m[1] = fmaxf(m[1], v[hh][1]);
      }
      fx2 sm = (fx2){0.f, 0.f};
#pragma unroll
      for (int hh = 0; hh < 8; hh++) {
        v[hh][0] = __expf(v[hh][0] - m[0]);
        v[hh][1] = __expf(v[hh][1] - m[1]);
        sm += v[hh];
      }
      const float inv0 = 1.0f / (sm[0] * 27.712812921102035f);  // / sqrt(768)
      const float inv1 = 1.0f / (sm[1] * 27.712812921102035f);
#pragma unroll
      for (int hh = 0; hh < 8; hh++) {
        bf16x2 pk;
        pk[0] = (bf16)(v[hh][0] * inv0);
        pk[1] = (bf16)(v[hh][1] * inv1);
        *(bf16x2*)&Pbuf[hh * 1280 + q * 40 + k2] = pk;
      }
    }
    barrier_nodrain();

    wait_vm6();

    bf16x8 bv[6];
#pragma unroll
    for (int j2 = 0; j2 < 6; j2++)
      bv[j2] = *(const bf16x8*)&Vl[q4 * 768 + (j2 * 16 + l15) * 8];

    bf16x8 ap[2];
#pragma unroll
    for (int i = 0; i < 2; i++)
      ap[i] = *(const bf16x8*)&Pbuf[h * 1280 + (i * 16 + l15) * 40 + q4 * 8];

    wait_lgkm0();
    stageV(kn);

    __builtin_amdgcn_s_setprio(1);
#pragma unroll
    for (int j2 = 0; j2 < 6; j2++) {
      o[0][j2] = MFMA16(ap[0], bv[j2], o[0][j2]);
      o[1][j2] = MFMA16(ap[1], bv[j2], o[1][j2]);
    }
    __builtin_amdgcn_s_setprio(0);
  }

  __builtin_amdgcn_s_waitcnt(0x0070);

#pragma unroll
  for (int i = 0; i < 2; i++)
#pragma unroll
    for (int j2 = 0; j2 < 6; j2++)
#pragma unroll
      for (int r = 0; r < 4; r++)
        AO[(size_t)(qrow0 + i * 16 + q4 * 4 + r) * 768 + h * 96 + j2 * 16 + l15] =
            (bf16)(o[i][j2][r]);
}

// ---------------------------------------------------------------------------
// Memory plan: d_out = xb + Ka. ws = Q + Va (+ Wb bf16 weights when
// ws_size >= 29,884,416 B — host-side runtime check; else R17 fallback).
// AO aliases Q.
// ---------------------------------------------------------------------------
extern "C" void kernel_launch(void* const* d_in, const int* in_sizes, int n_in,
                              void* d_out, int out_size, void* d_ws,
                              size_t ws_size, hipStream_t stream) {
  const float* x  = (const float*)d_in[0];
  const float* Wq = (const float*)d_in[1];
  const float* bq = (const float*)d_in[2];
  const float* Wk = (const float*)d_in[3];
  const float* bk = (const float*)d_in[4];
  const float* Wv = (const float*)d_in[5];
  const float* bv = (const float*)d_in[6];
  const float* Wo = (const float*)d_in[7];
  const float* bo = (const float*)d_in[8];

  const size_t MN = (size_t)8192 * 768;
  bf16* xb = (bf16*)d_out;
  bf16* Ka = xb + MN;
  bf16* Q  = (bf16*)d_ws;
  bf16* Va = Q + MN;
  bf16* AO = Q;  // aliases Q

  const size_t need_fast = MN * 2 * 2 + (size_t)4 * 589824 * 2;  // 29,884,416
  const bool fast = ws_size >= need_fast;
  bf16* Wb = Va + MN;  // tail of ws (only touched in fast path)

  if (fast) {
    cvt_all_kernel<<<8448, 256, 0, stream>>>(x, Wq, Wk, Wv, Wo, xb, Wb);
    dim3 qkvgrid(18, 64);
    gemm_qkv_bf<<<qkvgrid, 256, 0, stream>>>(xb, Wb, bq, bk, bv, Q, Ka, Va);
  } else {
    cvt_x_kernel<<<6144, 256, 0, stream>>>(x, xb);
    dim3 qkvgrid(18, 64);
    gemm_qkv<<<qkvgrid, 256, 0, stream>>>(xb, Wq, Wk, Wv, bq, bk, bv,
                                          Q, Ka, Va);
  }
  attn_kernel<<<256, 512, 0, stream>>>(Q, Ka, Va, AO);
  dim3 ogrid(6, 64);
  if (fast) {
    gemm_o_bf<<<ogrid, 256, 0, stream>>>(AO, Wb + (size_t)3 * 589824, bo,
                                         (float*)d_out);
  } else {
    gemm_o<<<ogrid, 256, 0, stream>>>(AO, Wo, bo, (float*)d_out);
  }
}